// Round 4
// baseline (348.924 us; speedup 1.0000x reference)
//
#include <hip/hip_runtime.h>
#include <hip/hip_bf16.h>

#define N_NODES 10000
#define KP      10240   // K padded to NT*BK; xwt pad cols are ZERO
#define F       128
#define BK      256     // K-tile in floats (1KB per row per tile -> DRAM page bursts)
#define NT      40      // KP / BK

typedef float  f32x4  __attribute__((ext_vector_type(4)));
typedef short  bf16x8 __attribute__((ext_vector_type(8)));
typedef short  s16x8  __attribute__((ext_vector_type(8)));

// f32 -> bf16 round-to-nearest-even (finite inputs only)
static __device__ __forceinline__ unsigned short f2bf(float f) {
    unsigned u = __builtin_bit_cast(unsigned, f);
    u += 0x7FFFu + ((u >> 16) & 1u);
    return (unsigned short)(u >> 16);
}

static __device__ __forceinline__ bf16x8 pack8(f32x4 lo, f32x4 hi) {
    bf16x8 r;
    r[0] = (short)f2bf(lo[0]); r[1] = (short)f2bf(lo[1]);
    r[2] = (short)f2bf(lo[2]); r[3] = (short)f2bf(lo[3]);
    r[4] = (short)f2bf(hi[0]); r[5] = (short)f2bf(hi[1]);
    r[6] = (short)f2bf(hi[2]); r[7] = (short)f2bf(hi[3]);
    return r;
}

// ---------------------------------------------------------------------------
// Kernel 1: xwt[f][n] = (X @ W1)[n][f] as bf16, transposed, zero-padded to KP.
// grid 640 x 256; each block does 16 nodes x 128 features. Pad nodes -> 0.
// ---------------------------------------------------------------------------
__global__ __launch_bounds__(256) void k_xw(const float* __restrict__ x,
                                            const float* __restrict__ W1,
                                            unsigned short* __restrict__ xwt) {
    __shared__ float xs[16][128];              // 8 KB
    __shared__ unsigned short ts[16][136];     // transpose staging (padded)
    const int t  = threadIdx.x;
    const int nb = blockIdx.x * 16;

    #pragma unroll
    for (int i = 0; i < 2; ++i) {
        int idx = t + i * 256;         // float4 index, 512 total
        int n   = idx >> 5;            // 32 float4 per row
        int c4  = idx & 31;
        int gn  = nb + n; if (gn > N_NODES - 1) gn = N_NODES - 1;
        f32x4 v = *reinterpret_cast<const f32x4*>(x + (size_t)gn * F + c4 * 4);
        *reinterpret_cast<f32x4*>(&xs[n][c4 * 4]) = v;
    }
    __syncthreads();

    const int f  = t & 127;
    const int ng = t >> 7;             // 0..1 -> nodes ng*8..+8
    float acc[8] = {0.f, 0.f, 0.f, 0.f, 0.f, 0.f, 0.f, 0.f};

    for (int c4 = 0; c4 < 32; ++c4) {
        float w0 = W1[(4 * c4 + 0) * F + f];
        float w1 = W1[(4 * c4 + 1) * F + f];
        float w2 = W1[(4 * c4 + 2) * F + f];
        float w3 = W1[(4 * c4 + 3) * F + f];
        #pragma unroll
        for (int i = 0; i < 8; ++i) {
            f32x4 xv = *reinterpret_cast<const f32x4*>(&xs[ng * 8 + i][c4 * 4]);
            acc[i] = fmaf(xv.x, w0, fmaf(xv.y, w1, fmaf(xv.z, w2, fmaf(xv.w, w3, acc[i]))));
        }
    }

    #pragma unroll
    for (int i = 0; i < 8; ++i) ts[ng * 8 + i][f] = f2bf(acc[i]);
    __syncthreads();

    {
        const int fo = t >> 1, h = t & 1;
        s16x8 v8;
        #pragma unroll
        for (int i = 0; i < 8; ++i) {
            int n = h * 8 + i;
            v8[i] = (nb + n < N_NODES) ? (short)ts[n][fo] : (short)0;
        }
        *reinterpret_cast<s16x8*>(xwt + (size_t)fo * KP + nb + h * 8) = v8;
    }
}

// ---------------------------------------------------------------------------
// Kernel 2: out[i] = relu(A @ XW + b1) @ W2 + b2, fused.
// grid 625 x 256; 16 rows/block, 4 waves split K within each 256-float tile.
// A staged to LDS in 1KB-per-row bursts (DRAM-page granular), bf16-converted,
// XOR-swizzled; double-buffered with one barrier per tile.
// ---------------------------------------------------------------------------
__global__ __launch_bounds__(256, 3) void k_gcn(const float* __restrict__ A,
                                                const unsigned short* __restrict__ xwt,
                                                const float* __restrict__ b1,
                                                const float* __restrict__ W2,
                                                const float* __restrict__ b2,
                                                float* __restrict__ out) {
    __shared__ unsigned short As[2][16 * BK];   // 2 x 8KB bf16 A-tiles, swizzled
    __shared__ float red[4][16][132];           // 33 KB cross-wave reduction

    const int t     = threadIdx.x;
    const int wave  = t >> 6;
    const int lane  = t & 63;
    const int l16   = lane & 15;
    const int g     = lane >> 4;        // 0..3
    const int rbase = blockIdx.x * 16;  // 10000 = 625*16 exactly

    // staging mapping: thread t loads 64B of row (t>>4) at chunk (t&15)
    const int srow = t >> 4;
    const int sc   = t & 15;
    const size_t rowbase = (size_t)(rbase + srow) * N_NODES + (size_t)sc * 16;
    const size_t alim    = (size_t)N_NODES * N_NODES - 4;   // clamp (f32x4)

    const unsigned short* bp0 = xwt + (size_t)l16 * KP + 8 * g;

    f32x4 acc[8];
    #pragma unroll
    for (int c = 0; c < 8; ++c) acc[c] = (f32x4){0.f, 0.f, 0.f, 0.f};

    f32x4 r0, r1, r2, r3;   // staged 64B (16 floats)

    auto LOADT = [&](int tile) {
        size_t base = rowbase + (size_t)tile * BK;
        size_t i0 = base;      if (i0 > alim) i0 = alim;
        size_t i1 = base + 4;  if (i1 > alim) i1 = alim;
        size_t i2 = base + 8;  if (i2 > alim) i2 = alim;
        size_t i3 = base + 12; if (i3 > alim) i3 = alim;
        r0 = __builtin_nontemporal_load(reinterpret_cast<const f32x4*>(A + i0));
        r1 = __builtin_nontemporal_load(reinterpret_cast<const f32x4*>(A + i1));
        r2 = __builtin_nontemporal_load(reinterpret_cast<const f32x4*>(A + i2));
        r3 = __builtin_nontemporal_load(reinterpret_cast<const f32x4*>(A + i3));
    };

    // LDS layout: 16B unit(row, k8) = row*32 + k8 (k8 = k/8), swizzled ^ (row&7)
    auto WRT = [&](int buf) {
        bf16x8 lo = pack8(r0, r1);
        bf16x8 hi = pack8(r2, r3);
        int u0 = (srow * 32 + sc * 2)     ^ (srow & 7);
        int u1 = (srow * 32 + sc * 2 + 1) ^ (srow & 7);
        *reinterpret_cast<bf16x8*>(&As[buf][u0 * 8]) = lo;
        *reinterpret_cast<bf16x8*>(&As[buf][u1 * 8]) = hi;
    };

    auto COMPUTE = [&](int tile, int buf) {
        #pragma unroll
        for (int j = 0; j < 2; ++j) {
            const int s  = wave + 4 * j;          // k-step 0..7 within tile
            const int kk = s * 32;
            const int u  = (l16 * 32 + (kk >> 3) + g) ^ (l16 & 7);
            bf16x8 af = *reinterpret_cast<const bf16x8*>(&As[buf][u * 8]);
            const unsigned short* bp = bp0 + (size_t)tile * BK + kk;
            #pragma unroll
            for (int c = 0; c < 8; ++c) {
                bf16x8 bf = *reinterpret_cast<const bf16x8*>(bp + (size_t)c * 16 * KP);
                acc[c] = __builtin_amdgcn_mfma_f32_16x16x32_bf16(af, bf, acc[c], 0, 0, 0);
            }
        }
    };

    // pipeline: tile t computes while tile t+1 is written and t+2 loads
    LOADT(0);
    WRT(0);
    LOADT(1);
    __syncthreads();
    for (int tile = 0; tile < NT; ++tile) {
        if (tile + 1 < NT) WRT((tile + 1) & 1);
        if (tile + 2 < NT) LOADT(tile + 2);
        COMPUTE(tile, tile & 1);
        __syncthreads();
    }

    // epilogue: cross-wave reduce + bias + relu + dot(W2) + b2
    // C/D layout (m89): col = lane&15, row = (lane>>4)*4 + reg
    #pragma unroll
    for (int c = 0; c < 8; ++c)
        #pragma unroll
        for (int e = 0; e < 4; ++e)
            red[wave][g * 4 + e][c * 16 + l16] = acc[c][e];
    __syncthreads();

    {
        const int r  = t >> 4;          // 0..15 local row
        const int jj = t & 15;          // 16 threads per row, 8 cols each
        float p = 0.f;
        #pragma unroll
        for (int i = 0; i < 8; ++i) {
            int c = jj * 8 + i;
            float v = red[0][r][c] + red[1][r][c] + red[2][r][c] + red[3][r][c] + b1[c];
            v = fmaxf(v, 0.f);
            p = fmaf(v, W2[c], p);
        }
        p += __shfl_xor(p, 1);
        p += __shfl_xor(p, 2);
        p += __shfl_xor(p, 4);
        p += __shfl_xor(p, 8);
        if (jj == 0) out[rbase + r] = p + b2[0];
    }
}

extern "C" void kernel_launch(void* const* d_in, const int* in_sizes, int n_in,
                              void* d_out, int out_size, void* d_ws, size_t ws_size,
                              hipStream_t stream) {
    const float* x  = (const float*)d_in[0];
    const float* a  = (const float*)d_in[1];
    const float* W1 = (const float*)d_in[2];
    const float* b1 = (const float*)d_in[3];
    const float* W2 = (const float*)d_in[4];
    const float* b2 = (const float*)d_in[5];
    float* out = (float*)d_out;
    unsigned short* xwt = (unsigned short*)d_ws;   // 128*10240*2 = 2.62 MB scratch

    k_xw<<<640, 256, 0, stream>>>(x, W1, xwt);     // 640*16 = 10240 cols (pad=0)
    k_gcn<<<625, 256, 0, stream>>>(a, xwt, b1, W2, b2, out);
}

// Round 5
// 187.375 us; speedup vs baseline: 1.8622x; 1.8622x over previous
//
#include <hip/hip_runtime.h>
#include <hip/hip_bf16.h>

#define N_NODES 10000
#define KP      10240   // K padded; xwt_t pad region is ZERO
#define F       128
#define BK      128     // K-tile
#define NT      80      // KP / BK

typedef float  f32x4  __attribute__((ext_vector_type(4)));
typedef short  bf16x8 __attribute__((ext_vector_type(8)));
typedef short  s16x8  __attribute__((ext_vector_type(8)));
typedef unsigned int u32x4 __attribute__((ext_vector_type(4)));

// f32 -> bf16 round-to-nearest-even (finite inputs only)
static __device__ __forceinline__ unsigned short f2bf(float f) {
    unsigned u = __builtin_bit_cast(unsigned, f);
    u += 0x7FFFu + ((u >> 16) & 1u);
    return (unsigned short)(u >> 16);
}

static __device__ __forceinline__ bf16x8 pack8(f32x4 lo, f32x4 hi) {
    bf16x8 r;
    r[0] = (short)f2bf(lo[0]); r[1] = (short)f2bf(lo[1]);
    r[2] = (short)f2bf(lo[2]); r[3] = (short)f2bf(lo[3]);
    r[4] = (short)f2bf(hi[0]); r[5] = (short)f2bf(hi[1]);
    r[6] = (short)f2bf(hi[2]); r[7] = (short)f2bf(hi[3]);
    return r;
}

// ---------------------------------------------------------------------------
// Kernel 1: xwt_t = (X @ W1)^T as bf16 in MFMA-native tiles:
//   xwt_t[kc][ct][c][k] : kc = k/32 (320), ct = col/16 (8), c = col%16, k = k%32
//   (tile = 16 cols x 32 k = 1KB contiguous; slab per kc = 8KB contiguous)
// grid 640 x 256; each block computes 16 nodes (k's) x 128 cols; pad k -> 0.
// ---------------------------------------------------------------------------
__global__ __launch_bounds__(256) void k_xw(const float* __restrict__ x,
                                            const float* __restrict__ W1,
                                            unsigned short* __restrict__ xwt) {
    __shared__ float xs[16][128];              // 8 KB
    __shared__ unsigned short ts[16][136];     // [node][col] staging (padded)
    const int t  = threadIdx.x;
    const int nb = blockIdx.x * 16;

    #pragma unroll
    for (int i = 0; i < 2; ++i) {
        int idx = t + i * 256;         // float4 index, 512 total
        int n   = idx >> 5;            // 32 float4 per row
        int c4  = idx & 31;
        int gn  = nb + n; if (gn > N_NODES - 1) gn = N_NODES - 1;
        f32x4 v = *reinterpret_cast<const f32x4*>(x + (size_t)gn * F + c4 * 4);
        *reinterpret_cast<f32x4*>(&xs[n][c4 * 4]) = v;
    }
    __syncthreads();

    const int f  = t & 127;
    const int ng = t >> 7;             // 0..1 -> nodes ng*8..+8
    float acc[8] = {0.f, 0.f, 0.f, 0.f, 0.f, 0.f, 0.f, 0.f};

    for (int c4 = 0; c4 < 32; ++c4) {
        float w0 = W1[(4 * c4 + 0) * F + f];
        float w1 = W1[(4 * c4 + 1) * F + f];
        float w2 = W1[(4 * c4 + 2) * F + f];
        float w3 = W1[(4 * c4 + 3) * F + f];
        #pragma unroll
        for (int i = 0; i < 8; ++i) {
            f32x4 xv = *reinterpret_cast<const f32x4*>(&xs[ng * 8 + i][c4 * 4]);
            acc[i] = fmaf(xv.x, w0, fmaf(xv.y, w1, fmaf(xv.z, w2, fmaf(xv.w, w3, acc[i]))));
        }
    }

    #pragma unroll
    for (int i = 0; i < 8; ++i) ts[ng * 8 + i][f] = f2bf(acc[i]);
    __syncthreads();

    // tiled write: thread t -> col = t>>1, node-half = t&1 (8 nodes along k)
    {
        const int col = t >> 1, half = t & 1;
        s16x8 v8;
        #pragma unroll
        for (int i = 0; i < 8; ++i) {
            int n = half * 8 + i;
            v8[i] = (nb + n < N_NODES) ? (short)ts[n][col] : (short)0;
        }
        const int kc = nb >> 5, khalf = (nb >> 4) & 1;
        size_t off = (size_t)kc * 4096 + (size_t)(col >> 4) * 512
                   + (size_t)(col & 15) * 32 + khalf * 16 + half * 8;
        *reinterpret_cast<s16x8*>(xwt + off) = v8;
    }
}

// ---------------------------------------------------------------------------
// Kernel 2: out = relu(A @ XW + b1) @ W2 + b2, fused.
// grid 625 x 256; 16 rows/block; 4 waves each own one 32-k step per BK=128 tile.
// BOTH operands staged to LDS (reg-staged, XOR-swizzled, double-buffered):
//   A: 16r x 128k f32 -> bf16 (4KB x2), B: 128k x 128c from tiled xwt (32KB x2).
// Hot loop has ZERO global loads in the MFMA dependency chain except staging.
// ---------------------------------------------------------------------------
__global__ __launch_bounds__(256, 2) void k_gcn(const float* __restrict__ A,
                                                const unsigned short* __restrict__ xwt,
                                                const float* __restrict__ b1,
                                                const float* __restrict__ W2,
                                                const float* __restrict__ b2,
                                                float* __restrict__ out) {
    __shared__ unsigned short As[2][16 * BK];              // 2 x 4 KB
    __shared__ __align__(16) unsigned char Bs[2][32768];   // 2 x 32 KB
    // epilogue reduction buffer overlays Bs (used only after final barrier)
    float (*red)[16][132] = reinterpret_cast<float (*)[16][132]>(&Bs[0][0]);

    const int t     = threadIdx.x;
    const int wave  = t >> 6;
    const int lane  = t & 63;
    const int l16   = lane & 15;
    const int g     = lane >> 4;        // 0..3
    const int rbase = blockIdx.x * 16;  // 10000 = 625*16 exactly

    // A staging: thread t loads 32B of row (t>>4) at k-chunk (t&15)*8
    const int sr = t >> 4;
    const int sc = t & 15;
    const size_t arow = (size_t)(rbase + sr) * N_NODES;
    const size_t alim = (size_t)N_NODES * N_NODES - 8;

    // MFMA fragment read offsets (16B units)
    const int aru = l16 * 16 + ((wave * 4 + g) ^ (l16 & 7));           // in As[buf]
    const int bru = wave * 512 + l16 * 4 + (g ^ ((l16 >> 1) & 3));     // in Bs[buf]

    f32x4 acc[8];
    #pragma unroll
    for (int c = 0; c < 8; ++c) acc[c] = (f32x4){0.f, 0.f, 0.f, 0.f};

    f32x4 a0, a1;       // A stage regs (32B)
    u32x4 bstg[8];      // B stage regs (128B), statically indexed via full unroll

    auto LOADT = [&](int tile) {
        size_t o = arow + (size_t)tile * BK + sc * 8;
        if (o > alim) o = alim;
        a0 = __builtin_nontemporal_load(reinterpret_cast<const f32x4*>(A + o));
        a1 = __builtin_nontemporal_load(reinterpret_cast<const f32x4*>(A + o) + 1);
        const u32x4* src = reinterpret_cast<const u32x4*>(xwt) + (size_t)tile * 2048 + t;
        #pragma unroll
        for (int i = 0; i < 8; ++i) bstg[i] = src[i * 256];
    };

    auto WRT = [&](int buf) {
        bf16x8 av = pack8(a0, a1);
        int au = sr * 16 + (sc ^ (sr & 7));
        *reinterpret_cast<bf16x8*>(&As[buf][au * 8]) = av;
        u32x4* bs = reinterpret_cast<u32x4*>(&Bs[buf][0]);
        #pragma unroll
        for (int i = 0; i < 8; ++i) {
            int u  = t + i * 256;
            int du = (u & ~3) | ((u ^ (u >> 3)) & 3);   // swizzle ku ^= (c>>1)&3
            bs[du] = bstg[i];
        }
    };

    auto COMPUTE = [&](int buf) {
        bf16x8 af = *reinterpret_cast<const bf16x8*>(&As[buf][aru * 8]);
        const u32x4* bs = reinterpret_cast<const u32x4*>(&Bs[buf][0]);
        #pragma unroll
        for (int c = 0; c < 8; ++c) {
            bf16x8 bf = *reinterpret_cast<const bf16x8*>(&bs[bru + c * 64]);
            acc[c] = __builtin_amdgcn_mfma_f32_16x16x32_bf16(af, bf, acc[c], 0, 0, 0);
        }
    };

    // 3-stage pipeline: compute(t) || write(t+1) || load(t+2)
    LOADT(0);
    WRT(0);
    LOADT(1);
    __syncthreads();
    for (int tile = 0; tile < NT; ++tile) {
        if (tile + 1 < NT) WRT((tile + 1) & 1);
        if (tile + 2 < NT) LOADT(tile + 2);
        COMPUTE(tile & 1);
        __syncthreads();
    }

    // epilogue: cross-wave reduce + bias + relu + dot(W2) + b2
    // C/D layout (m89): col = lane&15, row = (lane>>4)*4 + reg
    #pragma unroll
    for (int c = 0; c < 8; ++c)
        #pragma unroll
        for (int e = 0; e < 4; ++e)
            red[wave][g * 4 + e][c * 16 + l16] = acc[c][e];
    __syncthreads();

    {
        const int r  = t >> 4;          // 0..15 local row
        const int jj = t & 15;          // 16 threads per row, 8 cols each
        float p = 0.f;
        #pragma unroll
        for (int i = 0; i < 8; ++i) {
            int c = jj * 8 + i;
            float v = red[0][r][c] + red[1][r][c] + red[2][r][c] + red[3][r][c] + b1[c];
            v = fmaxf(v, 0.f);
            p = fmaf(v, W2[c], p);
        }
        p += __shfl_xor(p, 1);
        p += __shfl_xor(p, 2);
        p += __shfl_xor(p, 4);
        p += __shfl_xor(p, 8);
        if (jj == 0) out[rbase + r] = p + b2[0];
    }
}

extern "C" void kernel_launch(void* const* d_in, const int* in_sizes, int n_in,
                              void* d_out, int out_size, void* d_ws, size_t ws_size,
                              hipStream_t stream) {
    const float* x  = (const float*)d_in[0];
    const float* a  = (const float*)d_in[1];
    const float* W1 = (const float*)d_in[2];
    const float* b1 = (const float*)d_in[3];
    const float* W2 = (const float*)d_in[4];
    const float* b2 = (const float*)d_in[5];
    float* out = (float*)d_out;
    unsigned short* xwt = (unsigned short*)d_ws;   // 320*8KB = 2.62 MB tiled scratch

    k_xw<<<640, 256, 0, stream>>>(x, W1, xwt);     // fills all 320 kc-slabs (pad=0)
    k_gcn<<<625, 256, 0, stream>>>(a, xwt, b1, W2, b2, out);
}